// Round 16
// baseline (203.512 us; speedup 1.0000x reference)
//
#include <hip/hip_runtime.h>

// ---------------------------------------------------------------------------
// TextGraphSAGE: 2-layer SAGEConv (mean aggr), N=50000, D=768, H=128, C=4,
// E=800000.
//  - project BEFORE aggregating (mean commutes with linear map)
//  - CSR gather instead of scatter atomics (r1: 102M float atomics = 77%)
//  - r10-r15 lesson: gemm pinned at 112-125us across 6 structures. The
//    invariant: WRITE_SIZE 79MB vs 29MB useful -- scalar 2B bf16 C-stores
//    scattered across rows force read-modify-write of whole HBM lines.
//  - r16: C-epilogue staged through LDS (reuse As, padded [64][72]) then
//    row-contiguous 16B stores (128B/row = full lines, no RMW).
// ---------------------------------------------------------------------------

typedef __bf16 bf16x8 __attribute__((ext_vector_type(8)));
typedef float  f32x4  __attribute__((ext_vector_type(4)));

__device__ __forceinline__ float bf16_lo(uint32_t w) {
    union { uint32_t u; float f; } c; c.u = w << 16; return c.f;
}
__device__ __forceinline__ float bf16_hi(uint32_t w) {
    union { uint32_t u; float f; } c; c.u = w & 0xffff0000u; return c.f;
}

// ---- prep: Wb[256][768] bf16 row-major = concat(W1l, W1r); also zero deg.
__global__ __launch_bounds__(256)
void prep(const float* __restrict__ W1l, const float* __restrict__ W1r,
          __bf16* __restrict__ Wb, int* __restrict__ deg, int N)
{
    int i = blockIdx.x * 256 + threadIdx.x;
    if (i < N) deg[i] = 0;
    if (i < 256 * 768) {
        int n = i / 768, k = i - n * 768;
        float v = (n < 128) ? W1l[n * 768 + k] : W1r[(n - 128) * 768 + k];
        Wb[i] = (__bf16)v;
    }
}

// ---- CSR build step 1: degree histogram
__global__ __launch_bounds__(256)
void csr_count(const int* __restrict__ ei, int* __restrict__ deg, int E)
{
    int e = blockIdx.x * 256 + threadIdx.x;
    if (e >= E) return;
    atomicAdd(&deg[ei[E + e]], 1);
}

// ---- scan step 1: per-1024-block exclusive scan + block totals
__global__ __launch_bounds__(1024)
void scan1(const int* __restrict__ deg, int* __restrict__ row_ptr,
           int* __restrict__ partials, int N)
{
    __shared__ int buf[1024];
    int i = blockIdx.x * 1024 + threadIdx.x;
    int v = (i < N) ? deg[i] : 0;
    int val = v;
    buf[threadIdx.x] = val;
    __syncthreads();
    for (int off = 1; off < 1024; off <<= 1) {
        int t = (threadIdx.x >= (unsigned)off) ? buf[threadIdx.x - off] : 0;
        __syncthreads();
        val += t;
        buf[threadIdx.x] = val;
        __syncthreads();
    }
    if (i < N) row_ptr[i] = val - v;
    if (threadIdx.x == 1023) partials[blockIdx.x] = val;
}

// ---- scan steps 2+3 merged
__global__ __launch_bounds__(1024)
void scan23(int* __restrict__ row_ptr, int* __restrict__ cursor,
            const int* __restrict__ partials, int N, int E, int nb)
{
    __shared__ int soff;
    int b = blockIdx.x;
    if (threadIdx.x < 64) {
        int lane = threadIdx.x;
        int v = (lane < nb) ? partials[lane] : 0;
        int s = v;
        #pragma unroll
        for (int off = 1; off < 64; off <<= 1) {
            int t = __shfl_up(s, off);
            if (lane >= off) s += t;
        }
        if (lane == b) soff = s - v;
    }
    __syncthreads();
    int off = soff;
    int i = b * 1024 + threadIdx.x;
    if (i < N) {
        int v = row_ptr[i] + off;
        row_ptr[i] = v;
        cursor[i]  = v;
    }
    if (b == 0 && threadIdx.x == 0) row_ptr[N] = E;
}

// ---- fused: gemm tiles (blocks < gblocks) + csr_fill (blocks >= gblocks).
__global__ __launch_bounds__(256)
void gemm_fill(const float* __restrict__ A, const __bf16* __restrict__ Bw,
               __bf16* __restrict__ Cb, int M, int gblocks,
               const int* __restrict__ ei, int* __restrict__ cursor,
               int* __restrict__ csr_src, int E)
{
    constexpr int LDK = 72;                  // +8 bf16 pad (144B row stride)
    __shared__ __bf16 As[64][LDK];           // 9.2 KB (reused as C-stage)
    __shared__ __bf16 Bs[64][LDK];           // 9.2 KB
    const int tid = threadIdx.x;

    if ((int)blockIdx.x >= gblocks) {
        // ---------------- csr_fill path: one edge per thread ----------------
        int e = (blockIdx.x - gblocks) * 256 + tid;
        if (e < E) {
            int src = ei[e];
            int dst = ei[E + e];
            int pos = atomicAdd(&cursor[dst], 1);
            csr_src[pos] = src;
        }
        return;
    }

    // ---------------- gemm path ----------------
    // bijective XCD remap (m204): q=gblocks/8, rem=gblocks%8
    const int p   = blockIdx.x;
    const int xcd = p & 7, kk = p >> 3;
    const int q   = gblocks >> 3, rem = gblocks & 7;
    const int base = (xcd < rem) ? xcd * (q + 1) : rem * (q + 1) + (xcd - rem) * q;
    const int job = base + kk;
    const int bm  = (job >> 2) * 64;
    const int bn  = (job & 3) * 64;

    const int lane = tid & 63;
    const int wave = tid >> 6;
    const int wr = wave >> 1, wc = wave & 1; // wave tile: 32 rows x 32 cols
    const int l15 = lane & 15;
    const int lk  = lane >> 4;               // 0..3

    f32x4 acc[2][2] = {};
    float4 apref[2][2];
    bf16x8 bpref[2];

    auto load_tile = [&](int k0) {
        #pragma unroll
        for (int it = 0; it < 2; ++it) {
            int v = it * 256 + tid;
            int row = v >> 3, kc = (v & 7) << 3;
            if (bm + row < M) {
                const float* src = A + (size_t)(bm + row) * 768 + k0 + kc;
                apref[it][0] = *(const float4*)src;
                apref[it][1] = *(const float4*)(src + 4);
            } else {
                apref[it][0] = make_float4(0.f, 0.f, 0.f, 0.f);
                apref[it][1] = make_float4(0.f, 0.f, 0.f, 0.f);
            }
            bpref[it] = *(const bf16x8*)(Bw + (size_t)(bn + row) * 768 + k0 + kc);
        }
    };

    load_tile(0);
    for (int kt = 0; kt < 12; ++kt) {
        if (kt) __syncthreads();             // MFMA of kt-1 done with LDS
        #pragma unroll
        for (int it = 0; it < 2; ++it) {
            int v = it * 256 + tid;
            int row = v >> 3, kc = (v & 7) << 3;
            float4 f0 = apref[it][0], f1 = apref[it][1];
            bf16x8 b;
            b[0] = (__bf16)f0.x; b[1] = (__bf16)f0.y;
            b[2] = (__bf16)f0.z; b[3] = (__bf16)f0.w;
            b[4] = (__bf16)f1.x; b[5] = (__bf16)f1.y;
            b[6] = (__bf16)f1.z; b[7] = (__bf16)f1.w;
            *(bf16x8*)&As[row][kc] = b;
            *(bf16x8*)&Bs[row][kc] = bpref[it];
        }
        __syncthreads();
        if (kt < 11) load_tile((kt + 1) * 64);   // in flight across MFMA

        #pragma unroll
        for (int ks = 0; ks < 2; ++ks) {
            int koff = ks * 32 + lk * 8;
            bf16x8 af[2], bfr[2];
            #pragma unroll
            for (int i = 0; i < 2; ++i)
                af[i] = *(const bf16x8*)&As[wr * 32 + i * 16 + l15][koff];
            #pragma unroll
            for (int j = 0; j < 2; ++j)
                bfr[j] = *(const bf16x8*)&Bs[wc * 32 + j * 16 + l15][koff];
            #pragma unroll
            for (int i = 0; i < 2; ++i)
                #pragma unroll
                for (int j = 0; j < 2; ++j)
                    acc[i][j] = __builtin_amdgcn_mfma_f32_16x16x32_bf16(
                        af[i], bfr[j], acc[i][j], 0, 0, 0);
        }
    }

    // ---- coalesced C epilogue (r16): stage tile in LDS (reuse As), then
    // row-contiguous 16B stores (128B per tile row = full HBM lines).
    __syncthreads();                         // MFMA readers done with As
    // C/D layout: col = lane&15, row = (lane>>4)*4 + reg  [m89-verified]
    #pragma unroll
    for (int i = 0; i < 2; ++i)
        #pragma unroll
        for (int j = 0; j < 2; ++j)
            #pragma unroll
            for (int v = 0; v < 4; ++v)
                As[wr * 32 + i * 16 + lk * 4 + v][wc * 32 + j * 16 + l15] =
                    (__bf16)acc[i][j][v];
    __syncthreads();
    // 64 rows x 64 bf16 = 8 chunks of 16B per row; 512 chunks, 256 threads.
    #pragma unroll
    for (int it = 0; it < 2; ++it) {
        int idx = it * 256 + tid;
        int row = idx >> 3, ch = idx & 7;
        if (bm + row < M)
            *(bf16x8*)(Cb + (size_t)(bm + row) * 256 + bn + ch * 8) =
                *(const bf16x8*)&As[row][ch * 8];
    }
}

// ---- layer 1 + layer-2 projection, fused. One wave per node.
// 8 lanes per edge x 32B/lane (2 x uint4) -> 8 edges in flight / iteration.
__global__ __launch_bounds__(256)
void sage1_fused(const int* __restrict__ row_ptr, const int* __restrict__ csr_src,
                 const __bf16* __restrict__ pq, const float* __restrict__ b1,
                 const float* __restrict__ W2l, const float* __restrict__ W2r,
                 float* __restrict__ r, float* __restrict__ s, int N)
{
    __shared__ float Wl[512], Wr[512];
    for (int i = threadIdx.x; i < 512; i += 256) {
        Wl[i] = W2l[i];
        Wr[i] = W2r[i];
    }
    __syncthreads();

    int wid  = threadIdx.x >> 6;
    int lane = threadIdx.x & 63;
    int g = lane >> 3;          // edge slot 0..7
    int l = lane & 7;           // feature block 0..7
    int n = blockIdx.x * 4 + wid;
    if (n >= N) return;
    int beg = row_ptr[n], end = row_ptr[n + 1];

    float a0[8] = {}, a1[8] = {};   // feats l*8+j and 64+l*8+j
    for (int eb = beg; eb < end; eb += 64) {
        int cnt = min(64, end - eb);
        int id = (eb + lane < end) ? csr_src[eb + lane] : 0;
        for (int t = 0; t < cnt; t += 8) {
            int src = __shfl(id, t + g);
            if (t + g < cnt) {
                const __bf16* row = pq + (size_t)src * 256;
                uint4 w0 = *(const uint4*)(row + l * 8);
                uint4 w1 = *(const uint4*)(row + 64 + l * 8);
                a0[0] += bf16_lo(w0.x); a0[1] += bf16_hi(w0.x);
                a0[2] += bf16_lo(w0.y); a0[3] += bf16_hi(w0.y);
                a0[4] += bf16_lo(w0.z); a0[5] += bf16_hi(w0.z);
                a0[6] += bf16_lo(w0.w); a0[7] += bf16_hi(w0.w);
                a1[0] += bf16_lo(w1.x); a1[1] += bf16_hi(w1.x);
                a1[2] += bf16_lo(w1.y); a1[3] += bf16_hi(w1.y);
                a1[4] += bf16_lo(w1.z); a1[5] += bf16_hi(w1.z);
                a1[6] += bf16_lo(w1.w); a1[7] += bf16_hi(w1.w);
            }
        }
    }
    #pragma unroll
    for (int c = 0; c < 8; ++c) {
        a0[c] += __shfl_xor(a0[c], 8);  a1[c] += __shfl_xor(a1[c], 8);
        a0[c] += __shfl_xor(a0[c], 16); a1[c] += __shfl_xor(a1[c], 16);
        a0[c] += __shfl_xor(a0[c], 32); a1[c] += __shfl_xor(a1[c], 32);
    }

    float inv = 1.0f / fmaxf((float)(end - beg), 1.0f);
    const __bf16* qrow = pq + (size_t)n * 256 + 128;
    uint4  qw0 = *(const uint4*)(qrow + l * 8);
    uint4  qw1 = *(const uint4*)(qrow + 64 + l * 8);
    float4 bv00 = *(const float4*)(b1 + l * 8);
    float4 bv01 = *(const float4*)(b1 + l * 8 + 4);
    float4 bv10 = *(const float4*)(b1 + 64 + l * 8);
    float4 bv11 = *(const float4*)(b1 + 64 + l * 8 + 4);
    float h0[8], h1[8];
    h0[0] = fmaxf(a0[0] * inv + bv00.x + bf16_lo(qw0.x), 0.f);
    h0[1] = fmaxf(a0[1] * inv + bv00.y + bf16_hi(qw0.x), 0.f);
    h0[2] = fmaxf(a0[2] * inv + bv00.z + bf16_lo(qw0.y), 0.f);
    h0[3] = fmaxf(a0[3] * inv + bv00.w + bf16_hi(qw0.y), 0.f);
    h0[4] = fmaxf(a0[4] * inv + bv01.x + bf16_lo(qw0.z), 0.f);
    h0[5] = fmaxf(a0[5] * inv + bv01.y + bf16_hi(qw0.z), 0.f);
    h0[6] = fmaxf(a0[6] * inv + bv01.z + bf16_lo(qw0.w), 0.f);
    h0[7] = fmaxf(a0[7] * inv + bv01.w + bf16_hi(qw0.w), 0.f);
    h1[0] = fmaxf(a1[0] * inv + bv10.x + bf16_lo(qw1.x), 0.f);
    h1[1] = fmaxf(a1[1] * inv + bv10.y + bf16_hi(qw1.x), 0.f);
    h1[2] = fmaxf(a1[2] * inv + bv10.z + bf16_lo(qw1.y), 0.f);
    h1[3] = fmaxf(a1[3] * inv + bv10.w + bf16_hi(qw1.y), 0.f);
    h1[4] = fmaxf(a1[4] * inv + bv11.x + bf16_lo(qw1.z), 0.f);
    h1[5] = fmaxf(a1[5] * inv + bv11.y + bf16_hi(qw1.z), 0.f);
    h1[6] = fmaxf(a1[6] * inv + bv11.z + bf16_lo(qw1.w), 0.f);
    h1[7] = fmaxf(a1[7] * inv + bv11.w + bf16_hi(qw1.w), 0.f);

    float part[8];
    #pragma unroll
    for (int c = 0; c < 4; ++c) {
        float pl = 0.f, pr = 0.f;
        #pragma unroll
        for (int j = 0; j < 8; ++j) {
            pl = fmaf(h0[j], Wl[c * 128 + l * 8 + j], pl);
            pl = fmaf(h1[j], Wl[c * 128 + 64 + l * 8 + j], pl);
            pr = fmaf(h0[j], Wr[c * 128 + l * 8 + j], pr);
            pr = fmaf(h1[j], Wr[c * 128 + 64 + l * 8 + j], pr);
        }
        part[c] = pl; part[4 + c] = pr;
    }
    #pragma unroll
    for (int off = 4; off; off >>= 1)
        #pragma unroll
        for (int c = 0; c < 8; ++c)
            part[c] += __shfl_xor(part[c], off);
    if (lane == 0) {
        *(float4*)(r + (size_t)n * 4) = make_float4(part[0], part[1], part[2], part[3]);
        *(float4*)(s + (size_t)n * 4) = make_float4(part[4], part[5], part[6], part[7]);
    }
}

// ---- layer 2: out[n] = mean_{src} r[src] + b2 + s[n]
__global__ __launch_bounds__(256)
void sage2_gather(const int* __restrict__ row_ptr, const int* __restrict__ csr_src,
                  const float* __restrict__ r, const float* __restrict__ s,
                  const float* __restrict__ b2, float* __restrict__ out, int N)
{
    int t = blockIdx.x * 256 + threadIdx.x;
    if (t >= N * 4) return;
    int n = t >> 2, c = t & 3;
    int beg = row_ptr[n], end = row_ptr[n + 1];
    float acc = 0.f;
    for (int e = beg; e < end; ++e)
        acc += r[(size_t)csr_src[e] * 4 + c];
    out[t] = acc / fmaxf((float)(end - beg), 1.0f) + b2[c] + s[t];
}

extern "C" void kernel_launch(void* const* d_in, const int* in_sizes, int n_in,
                              void* d_out, int out_size, void* d_ws, size_t ws_size,
                              hipStream_t stream)
{
    const float* x   = (const float*)d_in[0];
    const int*   ei  = (const int*)d_in[1];
    const float* W1l = (const float*)d_in[2];
    const float* b1l = (const float*)d_in[3];
    const float* W1r = (const float*)d_in[4];
    const float* W2l = (const float*)d_in[5];
    const float* b2l = (const float*)d_in[6];
    const float* W2r = (const float*)d_in[7];
    float* out = (float*)d_out;

    const int N = in_sizes[0] / 768;   // 50000
    const int E = in_sizes[1] / 2;     // 800000
    const int NB = (N + 1023) / 1024;  // 49 scan blocks
    const int mtiles  = (N + 63) / 64; // 782 bm tiles
    const int gblocks = mtiles * 4;    // 3128 gemm blocks (x4 bn slices)
    const int fblocks = (E + 255) / 256; // 3125 fill blocks, 1 edge/thread

    char* ws = (char*)d_ws;
    size_t off = 0;
    auto alloc = [&](size_t bytes) -> void* {
        void* pp = ws + off;
        off += (bytes + 255) & ~(size_t)255;
        return pp;
    };
    __bf16* pq      = (__bf16*)alloc((size_t)N * 256 * 2);
    float*  r       = (float*)alloc((size_t)N * 4 * 4);
    float*  s       = (float*)alloc((size_t)N * 4 * 4);
    __bf16* Wb      = (__bf16*)alloc((size_t)256 * 768 * 2);
    int*    deg     = (int*)alloc((size_t)N * 4);
    int*    row_ptr = (int*)alloc((size_t)(N + 1) * 4);
    int*    cursor  = (int*)alloc((size_t)N * 4);
    int*    csr_src = (int*)alloc((size_t)E * 4);
    int*    partials= (int*)alloc((size_t)64 * 4);

    // ---- pack W row-major bf16 + zero deg
    prep<<<(256 * 768 + 255) / 256, 256, 0, stream>>>(W1l, W1r, Wb, deg, N);

    // ---- CSR: count + scans (fill happens inside gemm_fill)
    csr_count<<<(E + 255) / 256, 256, 0, stream>>>(ei, deg, E);
    scan1<<<NB, 1024, 0, stream>>>(deg, row_ptr, partials, N);
    scan23<<<NB, 1024, 0, stream>>>(row_ptr, cursor, partials, N, E, NB);

    // ---- fused layer-1 projection (+ coalesced C epilogue) + csr_fill
    gemm_fill<<<gblocks + fblocks, 256, 0, stream>>>(x, Wb, pq, N, gblocks,
                                                     ei, cursor, csr_src, E);

    // ---- layer 1 aggregate + epilogue + layer-2 projection (fused)
    sage1_fused<<<(N + 3) / 4, 256, 0, stream>>>(row_ptr, csr_src, pq, b1l,
                                                 W2l, W2r, r, s, N);

    // ---- layer 2 aggregate + epilogue
    sage2_gather<<<(N * 4 + 255) / 256, 256, 0, stream>>>(row_ptr, csr_src, r, s, b2l, out, N);
}

// Round 17
// 182.948 us; speedup vs baseline: 1.1124x; 1.1124x over previous
//
#include <hip/hip_runtime.h>

// ---------------------------------------------------------------------------
// TextGraphSAGE: 2-layer SAGEConv (mean aggr), N=50000, D=768, H=128, C=4,
// E=800000.
//  - project BEFORE aggregating (mean commutes with linear map)
//  - CSR gather instead of scatter atomics (r1: 102M float atomics = 77%)
//  - r10-r16 lesson: gemm pinned ~100-110us across 7 structures, no pipe
//    busy -> convoy effect (all resident blocks stall at barriers in
//    lockstep; per-tile compute < load latency, phases never decorrelate).
//    Phantom 50MB WRITE = fill-path atomics + random 4B scatters.
//  - r17: (1) per-block K-stagger (start tile = job%12) to break the
//    convoy; (2) slot-based atomic-free csr_fill (slot recorded in
//    csr_count; cursor eliminated).
// ---------------------------------------------------------------------------

typedef __bf16 bf16x8 __attribute__((ext_vector_type(8)));
typedef float  f32x4  __attribute__((ext_vector_type(4)));

__device__ __forceinline__ float bf16_lo(uint32_t w) {
    union { uint32_t u; float f; } c; c.u = w << 16; return c.f;
}
__device__ __forceinline__ float bf16_hi(uint32_t w) {
    union { uint32_t u; float f; } c; c.u = w & 0xffff0000u; return c.f;
}

// ---- prep: Wb[256][768] bf16 row-major = concat(W1l, W1r); also zero deg.
__global__ __launch_bounds__(256)
void prep(const float* __restrict__ W1l, const float* __restrict__ W1r,
          __bf16* __restrict__ Wb, int* __restrict__ deg, int N)
{
    int i = blockIdx.x * 256 + threadIdx.x;
    if (i < N) deg[i] = 0;
    if (i < 256 * 768) {
        int n = i / 768, k = i - n * 768;
        float v = (n < 128) ? W1l[n * 768 + k] : W1r[(n - 128) * 768 + k];
        Wb[i] = (__bf16)v;
    }
}

// ---- CSR build step 1: degree histogram + per-edge slot (r17)
__global__ __launch_bounds__(256)
void csr_count(const int* __restrict__ ei, int* __restrict__ deg,
               int* __restrict__ slot, int E)
{
    int e = blockIdx.x * 256 + threadIdx.x;
    if (e >= E) return;
    slot[e] = atomicAdd(&deg[ei[E + e]], 1);
}

// ---- scan step 1: per-1024-block exclusive scan + block totals
__global__ __launch_bounds__(1024)
void scan1(const int* __restrict__ deg, int* __restrict__ row_ptr,
           int* __restrict__ partials, int N)
{
    __shared__ int buf[1024];
    int i = blockIdx.x * 1024 + threadIdx.x;
    int v = (i < N) ? deg[i] : 0;
    int val = v;
    buf[threadIdx.x] = val;
    __syncthreads();
    for (int off = 1; off < 1024; off <<= 1) {
        int t = (threadIdx.x >= (unsigned)off) ? buf[threadIdx.x - off] : 0;
        __syncthreads();
        val += t;
        buf[threadIdx.x] = val;
        __syncthreads();
    }
    if (i < N) row_ptr[i] = val - v;
    if (threadIdx.x == 1023) partials[blockIdx.x] = val;
}

// ---- scan steps 2+3 merged (cursor no longer needed)
__global__ __launch_bounds__(1024)
void scan23(int* __restrict__ row_ptr, const int* __restrict__ partials,
            int N, int E, int nb)
{
    __shared__ int soff;
    int b = blockIdx.x;
    if (threadIdx.x < 64) {
        int lane = threadIdx.x;
        int v = (lane < nb) ? partials[lane] : 0;
        int s = v;
        #pragma unroll
        for (int off = 1; off < 64; off <<= 1) {
            int t = __shfl_up(s, off);
            if (lane >= off) s += t;
        }
        if (lane == b) soff = s - v;
    }
    __syncthreads();
    int off = soff;
    int i = b * 1024 + threadIdx.x;
    if (i < N) row_ptr[i] += off;
    if (b == 0 && threadIdx.x == 0) row_ptr[N] = E;
}

// ---- fused: gemm tiles (blocks < gblocks) + csr_fill (blocks >= gblocks,
// atomic-free: pos = row_ptr[dst] + slot[e]).
__global__ __launch_bounds__(256)
void gemm_fill(const float* __restrict__ A, const __bf16* __restrict__ Bw,
               __bf16* __restrict__ Cb, int M, int gblocks,
               const int* __restrict__ ei, const int* __restrict__ row_ptr,
               const int* __restrict__ slot, int* __restrict__ csr_src, int E)
{
    constexpr int LDK = 72;                  // +8 bf16 pad (144B row stride)
    __shared__ __bf16 As[64][LDK];           // 9.2 KB (reused as C-stage)
    __shared__ __bf16 Bs[64][LDK];           // 9.2 KB
    const int tid = threadIdx.x;

    if ((int)blockIdx.x >= gblocks) {
        // ------------- csr_fill: one edge per thread, NO atomics -------------
        int e = (blockIdx.x - gblocks) * 256 + tid;
        if (e < E) {
            int src = ei[e];
            int dst = ei[E + e];
            csr_src[row_ptr[dst] + slot[e]] = src;
        }
        return;
    }

    // ---------------- gemm path ----------------
    // bijective XCD remap (m204): q=gblocks/8, rem=gblocks%8
    const int p   = blockIdx.x;
    const int xcd = p & 7, kk = p >> 3;
    const int q   = gblocks >> 3, rem = gblocks & 7;
    const int base = (xcd < rem) ? xcd * (q + 1) : rem * (q + 1) + (xcd - rem) * q;
    const int job = base + kk;
    const int bm  = (job >> 2) * 64;
    const int bn  = (job & 3) * 64;
    // r17 convoy-breaker: this block starts its K-loop at tile job%12
    const int k0off = job % 12;

    const int lane = tid & 63;
    const int wave = tid >> 6;
    const int wr = wave >> 1, wc = wave & 1; // wave tile: 32 rows x 32 cols
    const int l15 = lane & 15;
    const int lk  = lane >> 4;               // 0..3

    f32x4 acc[2][2] = {};
    float4 apref[2][2];
    bf16x8 bpref[2];

    auto load_tile = [&](int k0) {
        #pragma unroll
        for (int it = 0; it < 2; ++it) {
            int v = it * 256 + tid;
            int row = v >> 3, kc = (v & 7) << 3;
            if (bm + row < M) {
                const float* src = A + (size_t)(bm + row) * 768 + k0 + kc;
                apref[it][0] = *(const float4*)src;
                apref[it][1] = *(const float4*)(src + 4);
            } else {
                apref[it][0] = make_float4(0.f, 0.f, 0.f, 0.f);
                apref[it][1] = make_float4(0.f, 0.f, 0.f, 0.f);
            }
            bpref[it] = *(const bf16x8*)(Bw + (size_t)(bn + row) * 768 + k0 + kc);
        }
    };

    load_tile(k0off * 64);
    for (int t = 0; t < 12; ++t) {
        const int kt  = (k0off + t) % 12;         // this iteration's K-tile
        const int ktn = (k0off + t + 1) % 12;     // next iteration's K-tile
        if (t) __syncthreads();              // MFMA of t-1 done with LDS
        #pragma unroll
        for (int it = 0; it < 2; ++it) {
            int v = it * 256 + tid;
            int row = v >> 3, kc = (v & 7) << 3;
            float4 f0 = apref[it][0], f1 = apref[it][1];
            bf16x8 b;
            b[0] = (__bf16)f0.x; b[1] = (__bf16)f0.y;
            b[2] = (__bf16)f0.z; b[3] = (__bf16)f0.w;
            b[4] = (__bf16)f1.x; b[5] = (__bf16)f1.y;
            b[6] = (__bf16)f1.z; b[7] = (__bf16)f1.w;
            *(bf16x8*)&As[row][kc] = b;
            *(bf16x8*)&Bs[row][kc] = bpref[it];
        }
        __syncthreads();
        if (t < 11) load_tile(ktn * 64);     // in flight across MFMA

        #pragma unroll
        for (int ks = 0; ks < 2; ++ks) {
            int koff = ks * 32 + lk * 8;
            bf16x8 af[2], bfr[2];
            #pragma unroll
            for (int i = 0; i < 2; ++i)
                af[i] = *(const bf16x8*)&As[wr * 32 + i * 16 + l15][koff];
            #pragma unroll
            for (int j = 0; j < 2; ++j)
                bfr[j] = *(const bf16x8*)&Bs[wc * 32 + j * 16 + l15][koff];
            #pragma unroll
            for (int i = 0; i < 2; ++i)
                #pragma unroll
                for (int j = 0; j < 2; ++j)
                    acc[i][j] = __builtin_amdgcn_mfma_f32_16x16x32_bf16(
                        af[i], bfr[j], acc[i][j], 0, 0, 0);
        }
    }

    // ---- coalesced C epilogue: stage tile in LDS (reuse As), then
    // row-contiguous 16B stores (128B per tile row = full HBM lines).
    __syncthreads();                         // MFMA readers done with As
    // C/D layout: col = lane&15, row = (lane>>4)*4 + reg  [m89-verified]
    #pragma unroll
    for (int i = 0; i < 2; ++i)
        #pragma unroll
        for (int j = 0; j < 2; ++j)
            #pragma unroll
            for (int v = 0; v < 4; ++v)
                As[wr * 32 + i * 16 + lk * 4 + v][wc * 32 + j * 16 + l15] =
                    (__bf16)acc[i][j][v];
    __syncthreads();
    #pragma unroll
    for (int it = 0; it < 2; ++it) {
        int idx = it * 256 + tid;
        int row = idx >> 3, ch = idx & 7;
        if (bm + row < M)
            *(bf16x8*)(Cb + (size_t)(bm + row) * 256 + bn + ch * 8) =
                *(const bf16x8*)&As[row][ch * 8];
    }
}

// ---- layer 1 + layer-2 projection, fused. One wave per node.
// 8 lanes per edge x 32B/lane (2 x uint4) -> 8 edges in flight / iteration.
__global__ __launch_bounds__(256)
void sage1_fused(const int* __restrict__ row_ptr, const int* __restrict__ csr_src,
                 const __bf16* __restrict__ pq, const float* __restrict__ b1,
                 const float* __restrict__ W2l, const float* __restrict__ W2r,
                 float* __restrict__ r, float* __restrict__ s, int N)
{
    __shared__ float Wl[512], Wr[512];
    for (int i = threadIdx.x; i < 512; i += 256) {
        Wl[i] = W2l[i];
        Wr[i] = W2r[i];
    }
    __syncthreads();

    int wid  = threadIdx.x >> 6;
    int lane = threadIdx.x & 63;
    int g = lane >> 3;          // edge slot 0..7
    int l = lane & 7;           // feature block 0..7
    int n = blockIdx.x * 4 + wid;
    if (n >= N) return;
    int beg = row_ptr[n], end = row_ptr[n + 1];

    float a0[8] = {}, a1[8] = {};   // feats l*8+j and 64+l*8+j
    for (int eb = beg; eb < end; eb += 64) {
        int cnt = min(64, end - eb);
        int id = (eb + lane < end) ? csr_src[eb + lane] : 0;
        for (int t = 0; t < cnt; t += 8) {
            int src = __shfl(id, t + g);
            if (t + g < cnt) {
                const __bf16* row = pq + (size_t)src * 256;
                uint4 w0 = *(const uint4*)(row + l * 8);
                uint4 w1 = *(const uint4*)(row + 64 + l * 8);
                a0[0] += bf16_lo(w0.x); a0[1] += bf16_hi(w0.x);
                a0[2] += bf16_lo(w0.y); a0[3] += bf16_hi(w0.y);
                a0[4] += bf16_lo(w0.z); a0[5] += bf16_hi(w0.z);
                a0[6] += bf16_lo(w0.w); a0[7] += bf16_hi(w0.w);
                a1[0] += bf16_lo(w1.x); a1[1] += bf16_hi(w1.x);
                a1[2] += bf16_lo(w1.y); a1[3] += bf16_hi(w1.y);
                a1[4] += bf16_lo(w1.z); a1[5] += bf16_hi(w1.z);
                a1[6] += bf16_lo(w1.w); a1[7] += bf16_hi(w1.w);
            }
        }
    }
    #pragma unroll
    for (int c = 0; c < 8; ++c) {
        a0[c] += __shfl_xor(a0[c], 8);  a1[c] += __shfl_xor(a1[c], 8);
        a0[c] += __shfl_xor(a0[c], 16); a1[c] += __shfl_xor(a1[c], 16);
        a0[c] += __shfl_xor(a0[c], 32); a1[c] += __shfl_xor(a1[c], 32);
    }

    float inv = 1.0f / fmaxf((float)(end - beg), 1.0f);
    const __bf16* qrow = pq + (size_t)n * 256 + 128;
    uint4  qw0 = *(const uint4*)(qrow + l * 8);
    uint4  qw1 = *(const uint4*)(qrow + 64 + l * 8);
    float4 bv00 = *(const float4*)(b1 + l * 8);
    float4 bv01 = *(const float4*)(b1 + l * 8 + 4);
    float4 bv10 = *(const float4*)(b1 + 64 + l * 8);
    float4 bv11 = *(const float4*)(b1 + 64 + l * 8 + 4);
    float h0[8], h1[8];
    h0[0] = fmaxf(a0[0] * inv + bv00.x + bf16_lo(qw0.x), 0.f);
    h0[1] = fmaxf(a0[1] * inv + bv00.y + bf16_hi(qw0.x), 0.f);
    h0[2] = fmaxf(a0[2] * inv + bv00.z + bf16_lo(qw0.y), 0.f);
    h0[3] = fmaxf(a0[3] * inv + bv00.w + bf16_hi(qw0.y), 0.f);
    h0[4] = fmaxf(a0[4] * inv + bv01.x + bf16_lo(qw0.z), 0.f);
    h0[5] = fmaxf(a0[5] * inv + bv01.y + bf16_hi(qw0.z), 0.f);
    h0[6] = fmaxf(a0[6] * inv + bv01.z + bf16_lo(qw0.w), 0.f);
    h0[7] = fmaxf(a0[7] * inv + bv01.w + bf16_hi(qw0.w), 0.f);
    h1[0] = fmaxf(a1[0] * inv + bv10.x + bf16_lo(qw1.x), 0.f);
    h1[1] = fmaxf(a1[1] * inv + bv10.y + bf16_hi(qw1.x), 0.f);
    h1[2] = fmaxf(a1[2] * inv + bv10.z + bf16_lo(qw1.y), 0.f);
    h1[3] = fmaxf(a1[3] * inv + bv10.w + bf16_hi(qw1.y), 0.f);
    h1[4] = fmaxf(a1[4] * inv + bv11.x + bf16_lo(qw1.z), 0.f);
    h1[5] = fmaxf(a1[5] * inv + bv11.y + bf16_hi(qw1.z), 0.f);
    h1[6] = fmaxf(a1[6] * inv + bv11.z + bf16_lo(qw1.w), 0.f);
    h1[7] = fmaxf(a1[7] * inv + bv11.w + bf16_hi(qw1.w), 0.f);

    float part[8];
    #pragma unroll
    for (int c = 0; c < 4; ++c) {
        float pl = 0.f, pr = 0.f;
        #pragma unroll
        for (int j = 0; j < 8; ++j) {
            pl = fmaf(h0[j], Wl[c * 128 + l * 8 + j], pl);
            pl = fmaf(h1[j], Wl[c * 128 + 64 + l * 8 + j], pl);
            pr = fmaf(h0[j], Wr[c * 128 + l * 8 + j], pr);
            pr = fmaf(h1[j], Wr[c * 128 + 64 + l * 8 + j], pr);
        }
        part[c] = pl; part[4 + c] = pr;
    }
    #pragma unroll
    for (int off = 4; off; off >>= 1)
        #pragma unroll
        for (int c = 0; c < 8; ++c)
            part[c] += __shfl_xor(part[c], off);
    if (lane == 0) {
        *(float4*)(r + (size_t)n * 4) = make_float4(part[0], part[1], part[2], part[3]);
        *(float4*)(s + (size_t)n * 4) = make_float4(part[4], part[5], part[6], part[7]);
    }
}

// ---- layer 2: out[n] = mean_{src} r[src] + b2 + s[n]
__global__ __launch_bounds__(256)
void sage2_gather(const int* __restrict__ row_ptr, const int* __restrict__ csr_src,
                  const float* __restrict__ r, const float* __restrict__ s,
                  const float* __restrict__ b2, float* __restrict__ out, int N)
{
    int t = blockIdx.x * 256 + threadIdx.x;
    if (t >= N * 4) return;
    int n = t >> 2, c = t & 3;
    int beg = row_ptr[n], end = row_ptr[n + 1];
    float acc = 0.f;
    for (int e = beg; e < end; ++e)
        acc += r[(size_t)csr_src[e] * 4 + c];
    out[t] = acc / fmaxf((float)(end - beg), 1.0f) + b2[c] + s[t];
}

extern "C" void kernel_launch(void* const* d_in, const int* in_sizes, int n_in,
                              void* d_out, int out_size, void* d_ws, size_t ws_size,
                              hipStream_t stream)
{
    const float* x   = (const float*)d_in[0];
    const int*   ei  = (const int*)d_in[1];
    const float* W1l = (const float*)d_in[2];
    const float* b1l = (const float*)d_in[3];
    const float* W1r = (const float*)d_in[4];
    const float* W2l = (const float*)d_in[5];
    const float* b2l = (const float*)d_in[6];
    const float* W2r = (const float*)d_in[7];
    float* out = (float*)d_out;

    const int N = in_sizes[0] / 768;   // 50000
    const int E = in_sizes[1] / 2;     // 800000
    const int NB = (N + 1023) / 1024;  // 49 scan blocks
    const int mtiles  = (N + 63) / 64; // 782 bm tiles
    const int gblocks = mtiles * 4;    // 3128 gemm blocks (x4 bn slices)
    const int fblocks = (E + 255) / 256; // 3125 fill blocks, 1 edge/thread

    char* ws = (char*)d_ws;
    size_t off = 0;
    auto alloc = [&](size_t bytes) -> void* {
        void* pp = ws + off;
        off += (bytes + 255) & ~(size_t)255;
        return pp;
    };
    __bf16* pq      = (__bf16*)alloc((size_t)N * 256 * 2);
    float*  r       = (float*)alloc((size_t)N * 4 * 4);
    float*  s       = (float*)alloc((size_t)N * 4 * 4);
    __bf16* Wb      = (__bf16*)alloc((size_t)256 * 768 * 2);
    int*    deg     = (int*)alloc((size_t)N * 4);
    int*    row_ptr = (int*)alloc((size_t)(N + 1) * 4);
    int*    slot    = (int*)alloc((size_t)E * 4);
    int*    csr_src = (int*)alloc((size_t)E * 4);
    int*    partials= (int*)alloc((size_t)64 * 4);

    // ---- pack W row-major bf16 + zero deg
    prep<<<(256 * 768 + 255) / 256, 256, 0, stream>>>(W1l, W1r, Wb, deg, N);

    // ---- CSR: count (+slot) + scans (fill happens inside gemm_fill)
    csr_count<<<(E + 255) / 256, 256, 0, stream>>>(ei, deg, slot, E);
    scan1<<<NB, 1024, 0, stream>>>(deg, row_ptr, partials, N);
    scan23<<<NB, 1024, 0, stream>>>(row_ptr, partials, N, E, NB);

    // ---- fused layer-1 projection (K-staggered) + atomic-free csr_fill
    gemm_fill<<<gblocks + fblocks, 256, 0, stream>>>(x, Wb, pq, N, gblocks,
                                                     ei, row_ptr, slot,
                                                     csr_src, E);

    // ---- layer 1 aggregate + epilogue + layer-2 projection (fused)
    sage1_fused<<<(N + 3) / 4, 256, 0, stream>>>(row_ptr, csr_src, pq, b1l,
                                                 W2l, W2r, r, s, N);

    // ---- layer 2 aggregate + epilogue
    sage2_gather<<<(N * 4 + 255) / 256, 256, 0, stream>>>(row_ptr, csr_src, r, s, b2l, out, N);
}